// Round 2
// baseline (12084.166 us; speedup 1.0000x reference)
//
#include <hip/hip_runtime.h>
#include <hip/hip_bf16.h>

#define N_NODES_DIM0 128

typedef unsigned short u16;
typedef unsigned int u32;

__device__ __forceinline__ float bf2f(u16 h) { return __uint_as_float((u32)h << 16); }
__device__ __forceinline__ u16 f2bf(float f) {
    u32 u = __float_as_uint(f);
    u32 r = (u + 0x7FFFu + ((u >> 16) & 1u)) >> 16;  // round-to-nearest-even
    return (u16)r;
}

// ---------------- degree / normalization ----------------

__global__ void deg_init_kernel(float* deg, int n) {
    int i = blockIdx.x * blockDim.x + threadIdx.x;
    if (i < n) deg[i] = 1.0f;  // self-loop contributes 1
}

__global__ void deg_accum_kernel(const int* __restrict__ dst, float* deg, int e) {
    int i = blockIdx.x * blockDim.x + threadIdx.x;
    if (i < e) atomicAdd(&deg[dst[i]], 1.0f);
}

__global__ void deg_to_dinv_kernel(float* deg, int n) {
    int i = blockIdx.x * blockDim.x + threadIdx.x;
    if (i < n) deg[i] = rsqrtf(deg[i]);  // deg >= 1 always
}

// ---------------- vector-4 loaders (fp32 / bf16) ----------------

template <typename T> struct Ld4;
template <> struct Ld4<float> {
    static __device__ __forceinline__ float4 load(const float* p) {
        return *reinterpret_cast<const float4*>(p);
    }
};
template <> struct Ld4<u16> {
    static __device__ __forceinline__ float4 load(const u16* p) {
        ushort4 u = *reinterpret_cast<const ushort4*>(p);
        return make_float4(bf2f(u.x), bf2f(u.y), bf2f(u.z), bf2f(u.w));
    }
};

// ---------------- GEMM chunk with dinv-scaled epilogue ----------------
// Gc[i, 0..Fc) = dinv[i] * (X[i,:] @ W[:, c0..c0+Fc))
// X:[N,K] row-major (fp32 or bf16), W:[K,F] row-major fp32. 64x64 block tile,
// BK=16, 256 threads, 4x4 microtile. grid.x = Fc/64.
template <typename TIn>
__global__ __launch_bounds__(256) void gemm_scaled_kernel(
    const TIn* __restrict__ X, const float* __restrict__ W,
    const float* __restrict__ dinv, float* __restrict__ Gc,
    int N, int K, int F, int c0, int Fc) {
    __shared__ float As[16][65];  // [k][m]
    __shared__ float Bs[16][65];  // [k][n]

    const int t = threadIdx.x;
    const int tx = t & 15;
    const int ty = t >> 4;
    const int row0 = blockIdx.y * 64;
    const int col0 = blockIdx.x * 64;  // within chunk

    float acc[4][4] = {};

    for (int k0 = 0; k0 < K; k0 += 16) {
        // A tile: 64 rows x 16 k
        {
            int r  = t >> 2;
            int kk = (t & 3) << 2;
            int gr = row0 + r;
            float4 v = make_float4(0.f, 0.f, 0.f, 0.f);
            if (gr < N)
                v = Ld4<TIn>::load(X + (size_t)gr * K + k0 + kk);
            As[kk + 0][r] = v.x; As[kk + 1][r] = v.y;
            As[kk + 2][r] = v.z; As[kk + 3][r] = v.w;
        }
        // B tile: 16 k x 64 cols
        {
            int kk = t >> 4;
            int c  = (t & 15) << 2;
            float4 v = *reinterpret_cast<const float4*>(
                W + (size_t)(k0 + kk) * F + c0 + col0 + c);
            Bs[kk][c + 0] = v.x; Bs[kk][c + 1] = v.y;
            Bs[kk][c + 2] = v.z; Bs[kk][c + 3] = v.w;
        }
        __syncthreads();
#pragma unroll
        for (int k = 0; k < 16; ++k) {
            float a[4], b[4];
#pragma unroll
            for (int i = 0; i < 4; ++i) a[i] = As[k][ty * 4 + i];
#pragma unroll
            for (int j = 0; j < 4; ++j) b[j] = Bs[k][tx * 4 + j];
#pragma unroll
            for (int i = 0; i < 4; ++i)
#pragma unroll
                for (int j = 0; j < 4; ++j)
                    acc[i][j] = fmaf(a[i], b[j], acc[i][j]);
        }
        __syncthreads();
    }

#pragma unroll
    for (int i = 0; i < 4; ++i) {
        int gr = row0 + ty * 4 + i;
        if (gr >= N) continue;
        float s = dinv[gr];
        float* out = Gc + (size_t)gr * Fc + col0 + tx * 4;
#pragma unroll
        for (int j = 0; j < 4; ++j) out[j] = s * acc[i][j];
    }
}

// ---------------- scatter-add over edges (chunk) ----------------
// ACCc[dst[e], :] += Gc[src[e], :]  (Fc columns, float4 granularity)
__global__ void scatter_add4_kernel(const int* __restrict__ src, const int* __restrict__ dst,
                                    const float* __restrict__ Gc, float* __restrict__ ACCc,
                                    long long total, int lgF4, int F4) {
    long long idx = (long long)blockIdx.x * blockDim.x + threadIdx.x;
    if (idx >= total) return;
    int e = (int)(idx >> lgF4);
    int j = (int)(idx & (F4 - 1));
    int s = src[e];
    int d = dst[e];
    float4 v = reinterpret_cast<const float4*>(Gc + (size_t)s * F4 * 4)[j];
    float* out = ACCc + (size_t)d * F4 * 4 + (size_t)j * 4;
    atomicAdd(out + 0, v.x);
    atomicAdd(out + 1, v.y);
    atomicAdd(out + 2, v.z);
    atomicAdd(out + 3, v.w);
}

// ---------------- finalize chunk: X_next[:, c0..c0+Fc) = relu(dinv*(acc+g)+b), bf16 out
__global__ void finalize_chunk_kernel(const float* __restrict__ ACCc, const float* __restrict__ Gc,
                                      const float* __restrict__ dinv, const float* __restrict__ bias,
                                      u16* __restrict__ XO, long long total, int lgF4, int F4,
                                      int c0, int Fnext) {
    long long idx = (long long)blockIdx.x * blockDim.x + threadIdx.x;
    if (idx >= total) return;
    int i  = (int)(idx >> lgF4);
    int j4 = (int)(idx & (F4 - 1));
    float4 a = reinterpret_cast<const float4*>(ACCc)[idx];
    float4 g = reinterpret_cast<const float4*>(Gc)[idx];
    float4 b = *reinterpret_cast<const float4*>(bias + c0 + j4 * 4);
    float s = dinv[i];
    ushort4 r;
    r.x = f2bf(fmaxf(s * (a.x + g.x) + b.x, 0.f));
    r.y = f2bf(fmaxf(s * (a.y + g.y) + b.y, 0.f));
    r.z = f2bf(fmaxf(s * (a.z + g.z) + b.z, 0.f));
    r.w = f2bf(fmaxf(s * (a.w + g.w) + b.w, 0.f));
    *reinterpret_cast<ushort4*>(XO + (size_t)i * Fnext + c0 + j4 * 4) = r;
}

// ---------------- layer 5 (F_out = 1), bf16 input ----------------
__global__ void layer5_dot_kernel(const u16* __restrict__ X, const float* __restrict__ W5,
                                  const float* __restrict__ dinv, float* __restrict__ g5, int N) {
    int gtid = blockIdx.x * blockDim.x + threadIdx.x;
    int node = gtid >> 6;
    int lane = threadIdx.x & 63;
    if (node >= N) return;
    float v = bf2f(X[(size_t)node * 64 + lane]) * W5[lane];
#pragma unroll
    for (int off = 32; off > 0; off >>= 1) v += __shfl_down(v, off, 64);
    if (lane == 0) g5[node] = dinv[node] * v;
}

__global__ void scatter1_kernel(const int* __restrict__ src, const int* __restrict__ dst,
                                const float* __restrict__ g5, float* __restrict__ acc1, int e) {
    int i = blockIdx.x * blockDim.x + threadIdx.x;
    if (i < e) atomicAdd(&acc1[dst[i]], g5[src[i]]);
}

__global__ void finalize5_kernel(const float* __restrict__ acc1, const float* __restrict__ g5,
                                 const float* __restrict__ dinv, const float* __restrict__ b5,
                                 float* __restrict__ out, int N) {
    int i = blockIdx.x * blockDim.x + threadIdx.x;
    if (i >= N) return;
    float v = dinv[i] * (acc1[i] + g5[i]) + b5[0];
    out[i] = fmaxf(v, 0.f);
}

// ---------------- launch ----------------

static inline size_t align_up(size_t x) { return (x + 255) & ~(size_t)255; }

extern "C" void kernel_launch(void* const* d_in, const int* in_sizes, int n_in,
                              void* d_out, int out_size, void* d_ws, size_t ws_size,
                              hipStream_t stream) {
    const float* x  = (const float*)d_in[0];
    const int*   ei = (const int*)d_in[1];
    const int E = in_sizes[1] / 2;
    const int N = in_sizes[0] / N_NODES_DIM0;
    const int* src = ei;
    const int* dst = ei + E;

    const float* W[5] = {(const float*)d_in[2], (const float*)d_in[4], (const float*)d_in[6],
                         (const float*)d_in[8], (const float*)d_in[10]};
    const float* B[5] = {(const float*)d_in[3], (const float*)d_in[5], (const float*)d_in[7],
                         (const float*)d_in[9], (const float*)d_in[11]};

    // workspace carve — peak ~206 MB
    char* w = (char*)d_ws;
    size_t off = 0;
    float* dinv = (float*)(w + off); off += align_up((size_t)N * 4);
    float* g5   = (float*)(w + off); off += align_up((size_t)N * 4);
    float* acc1 = (float*)(w + off); off += align_up((size_t)N * 4);
    float* Gc   = (float*)(w + off); off += align_up((size_t)N * 128 * 4);   // 25.6 MB
    float* ACCc = (float*)(w + off); off += align_up((size_t)N * 128 * 4);   // 25.6 MB
    u16*   XA   = (u16*)(w + off);   off += align_up((size_t)N * 1024 * 2);  // 102.4 MB
    u16*   XB   = (u16*)(w + off);   off += align_up((size_t)N * 512 * 2);   // 51.2 MB
    (void)ws_size;

    // degree -> dinv
    deg_init_kernel<<<(N + 255) / 256, 256, 0, stream>>>(dinv, N);
    deg_accum_kernel<<<(E + 255) / 256, 256, 0, stream>>>(dst, dinv, E);
    deg_to_dinv_kernel<<<(N + 255) / 256, 256, 0, stream>>>(dinv, N);

    const int Ks[4] = {128, 1024, 512, 256};
    const int Fs[4] = {1024, 512, 256, 64};
    u16* Xout[4] = {XA, XB, XA, XB};  // X1->A, X2->B, X3->A (X1 dead), X4->B (X2 dead)

    for (int l = 0; l < 4; ++l) {
        const int K = Ks[l], F = Fs[l];
        u16* XO = Xout[l];
        const int Fc = (F < 128) ? F : 128;
        const int F4 = Fc / 4;
        const int lg = 31 - __builtin_clz(F4);
        const long long totE = (long long)E * F4;
        const long long totN = (long long)N * F4;

        for (int c0 = 0; c0 < F; c0 += Fc) {
            dim3 grid(Fc / 64, (N + 63) / 64);
            if (l == 0) {
                gemm_scaled_kernel<float><<<grid, 256, 0, stream>>>(
                    x, W[l], dinv, Gc, N, K, F, c0, Fc);
            } else {
                gemm_scaled_kernel<u16><<<grid, 256, 0, stream>>>(
                    Xout[l - 1], W[l], dinv, Gc, N, K, F, c0, Fc);
            }

            hipMemsetAsync(ACCc, 0, (size_t)N * Fc * 4, stream);

            scatter_add4_kernel<<<(unsigned)((totE + 255) / 256), 256, 0, stream>>>(
                src, dst, Gc, ACCc, totE, lg, F4);

            finalize_chunk_kernel<<<(unsigned)((totN + 255) / 256), 256, 0, stream>>>(
                ACCc, Gc, dinv, B[l], XO, totN, lg, F4, c0, F);
        }
    }

    // layer 5: [N,64](bf16) @ [64,1]
    layer5_dot_kernel<<<(N * 64 + 255) / 256, 256, 0, stream>>>(XB, W[4], dinv, g5, N);
    hipMemsetAsync(acc1, 0, (size_t)N * 4, stream);
    scatter1_kernel<<<(E + 255) / 256, 256, 0, stream>>>(src, dst, g5, acc1, E);
    finalize5_kernel<<<(N + 255) / 256, 256, 0, stream>>>(acc1, g5, dinv, B[4],
                                                          (float*)d_out, N);
}

// Round 3
// 2777.712 us; speedup vs baseline: 4.3504x; 4.3504x over previous
//
#include <hip/hip_runtime.h>
#include <hip/hip_bf16.h>

#define N_NODES_DIM0 128

typedef unsigned short u16;
typedef unsigned int u32;

__device__ __forceinline__ float bf2f(u16 h) { return __uint_as_float((u32)h << 16); }
__device__ __forceinline__ u16 f2bf(float f) {
    u32 u = __float_as_uint(f);
    u32 r = (u + 0x7FFFu + ((u >> 16) & 1u)) >> 16;  // round-to-nearest-even
    return (u16)r;
}

// ---------------- CSR build ----------------

__global__ void zero_int_kernel(int* p, int n) {
    int i = blockIdx.x * blockDim.x + threadIdx.x;
    if (i < n) p[i] = 0;
}

__global__ void hist_kernel(const int* __restrict__ dst, int* __restrict__ cnt, int e) {
    int i = blockIdx.x * blockDim.x + threadIdx.x;
    if (i < e) atomicAdd(&cnt[dst[i]], 1);
}

// single-workgroup chunked exclusive scan: row_ptr[0..n], row_ptr[n] = total
__global__ __launch_bounds__(1024) void scan_kernel(const int* __restrict__ cnt,
                                                    int* __restrict__ row_ptr, int n) {
    __shared__ int buf[1024];
    __shared__ int carry_s;
    const int t = threadIdx.x;
    if (t == 0) carry_s = 0;
    __syncthreads();
    for (int base = 0; base < n; base += 1024) {
        int i = base + t;
        int v = (i < n) ? cnt[i] : 0;
        buf[t] = v;
        __syncthreads();
#pragma unroll
        for (int off = 1; off < 1024; off <<= 1) {
            int x = (t >= off) ? buf[t - off] : 0;
            __syncthreads();
            buf[t] += x;
            __syncthreads();
        }
        int carry = carry_s;
        if (i < n) row_ptr[i] = carry + buf[t] - v;  // exclusive
        __syncthreads();
        if (t == 0) carry_s = carry + buf[1023];
        __syncthreads();
    }
    if (t == 0) row_ptr[n] = carry_s;
}

__global__ void fill_kernel(const int* __restrict__ src, const int* __restrict__ dst,
                            const int* __restrict__ row_ptr, int* __restrict__ fill,
                            int* __restrict__ csr_src, int e) {
    int i = blockIdx.x * blockDim.x + threadIdx.x;
    if (i < e) {
        int d = dst[i];
        int pos = row_ptr[d] + atomicAdd(&fill[d], 1);
        csr_src[pos] = src[i];
    }
}

__global__ void dinv_kernel(const int* __restrict__ row_ptr, float* __restrict__ dinv, int n) {
    int i = blockIdx.x * blockDim.x + threadIdx.x;
    if (i < n) dinv[i] = rsqrtf((float)(row_ptr[i + 1] - row_ptr[i]) + 1.0f);
}

// ---------------- vector-4 loaders (fp32 / bf16) ----------------

template <typename T> struct Ld4;
template <> struct Ld4<float> {
    static __device__ __forceinline__ float4 load(const float* p) {
        return *reinterpret_cast<const float4*>(p);
    }
};
template <> struct Ld4<u16> {
    static __device__ __forceinline__ float4 load(const u16* p) {
        ushort4 u = *reinterpret_cast<const ushort4*>(p);
        return make_float4(bf2f(u.x), bf2f(u.y), bf2f(u.z), bf2f(u.w));
    }
};

// ---------------- GEMM chunk with dinv-scaled epilogue ----------------
// Gc[i, 0..Fc) = dinv[i] * (X[i,:] @ W[:, c0..c0+Fc))
template <typename TIn>
__global__ __launch_bounds__(256) void gemm_scaled_kernel(
    const TIn* __restrict__ X, const float* __restrict__ W,
    const float* __restrict__ dinv, float* __restrict__ Gc,
    int N, int K, int F, int c0, int Fc) {
    __shared__ float As[16][65];  // [k][m]
    __shared__ float Bs[16][65];  // [k][n]

    const int t = threadIdx.x;
    const int tx = t & 15;
    const int ty = t >> 4;
    const int row0 = blockIdx.y * 64;
    const int col0 = blockIdx.x * 64;  // within chunk

    float acc[4][4] = {};

    for (int k0 = 0; k0 < K; k0 += 16) {
        {
            int r  = t >> 2;
            int kk = (t & 3) << 2;
            int gr = row0 + r;
            float4 v = make_float4(0.f, 0.f, 0.f, 0.f);
            if (gr < N)
                v = Ld4<TIn>::load(X + (size_t)gr * K + k0 + kk);
            As[kk + 0][r] = v.x; As[kk + 1][r] = v.y;
            As[kk + 2][r] = v.z; As[kk + 3][r] = v.w;
        }
        {
            int kk = t >> 4;
            int c  = (t & 15) << 2;
            float4 v = *reinterpret_cast<const float4*>(
                W + (size_t)(k0 + kk) * F + c0 + col0 + c);
            Bs[kk][c + 0] = v.x; Bs[kk][c + 1] = v.y;
            Bs[kk][c + 2] = v.z; Bs[kk][c + 3] = v.w;
        }
        __syncthreads();
#pragma unroll
        for (int k = 0; k < 16; ++k) {
            float a[4], b[4];
#pragma unroll
            for (int i = 0; i < 4; ++i) a[i] = As[k][ty * 4 + i];
#pragma unroll
            for (int j = 0; j < 4; ++j) b[j] = Bs[k][tx * 4 + j];
#pragma unroll
            for (int i = 0; i < 4; ++i)
#pragma unroll
                for (int j = 0; j < 4; ++j)
                    acc[i][j] = fmaf(a[i], b[j], acc[i][j]);
        }
        __syncthreads();
    }

#pragma unroll
    for (int i = 0; i < 4; ++i) {
        int gr = row0 + ty * 4 + i;
        if (gr >= N) continue;
        float s = dinv[gr];
        float* out = Gc + (size_t)gr * Fc + col0 + tx * 4;
#pragma unroll
        for (int j = 0; j < 4; ++j) out[j] = s * acc[i][j];
    }
}

// ---------------- fused CSR aggregation + finalize ----------------
// For dst node d: acc = Gc[d,:] + sum_{e in CSR[d]} Gc[src_e,:]
// X_next[d, c0+j] = bf16(relu(dinv[d]*acc[j] + b[c0+j]))
// FC cols per chunk; LPN = FC/2 lanes per node (float2 each); 256 thr/block.
template <int FC>
__global__ __launch_bounds__(256) void agg_kernel(
    const int* __restrict__ row_ptr, const int* __restrict__ csr_src,
    const float* __restrict__ Gc, const float* __restrict__ dinv,
    const float* __restrict__ bias, u16* __restrict__ XO,
    int N, int c0, int Fnext) {
    constexpr int LPN = FC / 2;
    constexpr int NPB = 256 / LPN;
    int node = blockIdx.x * NPB + threadIdx.x / LPN;
    int lane = threadIdx.x % LPN;
    if (node >= N) return;

    int beg = row_ptr[node];
    int end = row_ptr[node + 1];

    float2 acc = *reinterpret_cast<const float2*>(Gc + (size_t)node * FC + lane * 2);  // self-loop
    for (int e = beg; e < end; ++e) {
        int s = csr_src[e];
        float2 v = *reinterpret_cast<const float2*>(Gc + (size_t)s * FC + lane * 2);
        acc.x += v.x;
        acc.y += v.y;
    }
    float dv = dinv[node];
    float2 b = *reinterpret_cast<const float2*>(bias + c0 + lane * 2);
    ushort2 r;
    r.x = f2bf(fmaxf(fmaf(dv, acc.x, b.x), 0.f));
    r.y = f2bf(fmaxf(fmaf(dv, acc.y, b.y), 0.f));
    *reinterpret_cast<ushort2*>(XO + (size_t)node * Fnext + c0 + lane * 2) = r;
}

// ---------------- layer 5 (F_out = 1) ----------------
__global__ void layer5_dot_kernel(const u16* __restrict__ X, const float* __restrict__ W5,
                                  const float* __restrict__ dinv, float* __restrict__ g5, int N) {
    int gtid = blockIdx.x * blockDim.x + threadIdx.x;
    int node = gtid >> 6;
    int lane = threadIdx.x & 63;
    if (node >= N) return;
    float v = bf2f(X[(size_t)node * 64 + lane]) * W5[lane];
#pragma unroll
    for (int off = 32; off > 0; off >>= 1) v += __shfl_down(v, off, 64);
    if (lane == 0) g5[node] = dinv[node] * v;
}

__global__ void agg5_kernel(const int* __restrict__ row_ptr, const int* __restrict__ csr_src,
                            const float* __restrict__ g5, const float* __restrict__ dinv,
                            const float* __restrict__ b5, float* __restrict__ out, int N) {
    int i = blockIdx.x * blockDim.x + threadIdx.x;
    if (i >= N) return;
    float acc = g5[i];
    for (int e = row_ptr[i]; e < row_ptr[i + 1]; ++e) acc += g5[csr_src[e]];
    out[i] = fmaxf(fmaf(dinv[i], acc, b5[0]), 0.f);
}

// ---------------- launch ----------------

static inline size_t align_up(size_t x) { return (x + 255) & ~(size_t)255; }

extern "C" void kernel_launch(void* const* d_in, const int* in_sizes, int n_in,
                              void* d_out, int out_size, void* d_ws, size_t ws_size,
                              hipStream_t stream) {
    const float* x  = (const float*)d_in[0];
    const int*   ei = (const int*)d_in[1];
    const int E = in_sizes[1] / 2;
    const int N = in_sizes[0] / N_NODES_DIM0;
    const int* src = ei;
    const int* dst = ei + E;

    const float* W[5] = {(const float*)d_in[2], (const float*)d_in[4], (const float*)d_in[6],
                         (const float*)d_in[8], (const float*)d_in[10]};
    const float* B[5] = {(const float*)d_in[3], (const float*)d_in[5], (const float*)d_in[7],
                         (const float*)d_in[9], (const float*)d_in[11]};

    // workspace carve — peak ~182 MB
    char* w = (char*)d_ws;
    size_t off = 0;
    float* dinv    = (float*)(w + off); off += align_up((size_t)N * 4);
    float* g5      = (float*)(w + off); off += align_up((size_t)N * 4);
    int*   cnt     = (int*)(w + off);   off += align_up((size_t)N * 4);        // also reused as fill[]
    int*   row_ptr = (int*)(w + off);   off += align_up((size_t)(N + 1) * 4);
    int*   csr_src = (int*)(w + off);   off += align_up((size_t)E * 4);        // 1.6 MB
    float* Gc      = (float*)(w + off); off += align_up((size_t)N * 128 * 4);  // 25.6 MB
    u16*   XA      = (u16*)(w + off);   off += align_up((size_t)N * 1024 * 2); // 102.4 MB
    u16*   XB      = (u16*)(w + off);   off += align_up((size_t)N * 512 * 2);  // 51.2 MB
    (void)ws_size;

    // ---- CSR build (dst-sorted) ----
    zero_int_kernel<<<(N + 255) / 256, 256, 0, stream>>>(cnt, N);
    hist_kernel<<<(E + 255) / 256, 256, 0, stream>>>(dst, cnt, E);
    scan_kernel<<<1, 1024, 0, stream>>>(cnt, row_ptr, N);
    zero_int_kernel<<<(N + 255) / 256, 256, 0, stream>>>(cnt, N);  // reuse as fill
    fill_kernel<<<(E + 255) / 256, 256, 0, stream>>>(src, dst, row_ptr, cnt, csr_src, E);
    dinv_kernel<<<(N + 255) / 256, 256, 0, stream>>>(row_ptr, dinv, N);

    const int Ks[4] = {128, 1024, 512, 256};
    const int Fs[4] = {1024, 512, 256, 64};
    u16* Xout[4] = {XA, XB, XA, XB};  // X1->A, X2->B, X3->A (X1 dead), X4->B (X2 dead)

    for (int l = 0; l < 4; ++l) {
        const int K = Ks[l], F = Fs[l];
        u16* XO = Xout[l];
        const int Fc = (F < 128) ? F : 128;

        for (int c0 = 0; c0 < F; c0 += Fc) {
            dim3 grid(Fc / 64, (N + 63) / 64);
            if (l == 0) {
                gemm_scaled_kernel<float><<<grid, 256, 0, stream>>>(
                    x, W[l], dinv, Gc, N, K, F, c0, Fc);
            } else {
                gemm_scaled_kernel<u16><<<grid, 256, 0, stream>>>(
                    Xout[l - 1], W[l], dinv, Gc, N, K, F, c0, Fc);
            }

            if (Fc == 128) {
                int npb = 256 / (128 / 2);  // 4 nodes/block
                agg_kernel<128><<<(N + npb - 1) / npb, 256, 0, stream>>>(
                    row_ptr, csr_src, Gc, dinv, B[l], XO, N, c0, F);
            } else {  // Fc == 64
                int npb = 256 / (64 / 2);   // 8 nodes/block
                agg_kernel<64><<<(N + npb - 1) / npb, 256, 0, stream>>>(
                    row_ptr, csr_src, Gc, dinv, B[l], XO, N, c0, F);
            }
        }
    }

    // layer 5: [N,64](bf16) @ [64,1]
    layer5_dot_kernel<<<(N * 64 + 255) / 256, 256, 0, stream>>>(XB, W[4], dinv, g5, N);
    agg5_kernel<<<(N + 255) / 256, 256, 0, stream>>>(row_ptr, csr_src, g5, dinv, B[4],
                                                     (float*)d_out, N);
}

// Round 4
// 622.840 us; speedup vs baseline: 19.4017x; 4.4597x over previous
//
#include <hip/hip_runtime.h>
#include <hip/hip_bf16.h>

#define N_NODES_DIM0 128

typedef unsigned short u16;
typedef unsigned int u32;
typedef __attribute__((ext_vector_type(8))) short short8;
typedef __attribute__((ext_vector_type(4))) float f32x4;

__device__ __forceinline__ float bf2f(u16 h) { return __uint_as_float((u32)h << 16); }
__device__ __forceinline__ u16 f2bf(float f) {
    u32 u = __float_as_uint(f);
    u32 r = (u + 0x7FFFu + ((u >> 16) & 1u)) >> 16;  // round-to-nearest-even
    return (u16)r;
}

// ---------------- CSR build ----------------

__global__ void zero_int_kernel(int* p, int n) {
    int i = blockIdx.x * blockDim.x + threadIdx.x;
    if (i < n) p[i] = 0;
}

__global__ void hist_kernel(const int* __restrict__ dst, int* __restrict__ cnt, int e) {
    int i = blockIdx.x * blockDim.x + threadIdx.x;
    if (i < e) atomicAdd(&cnt[dst[i]], 1);
}

// single-workgroup chunked exclusive scan: row_ptr[0..n], row_ptr[n] = total
__global__ __launch_bounds__(1024) void scan_kernel(const int* __restrict__ cnt,
                                                    int* __restrict__ row_ptr, int n) {
    __shared__ int buf[1024];
    __shared__ int carry_s;
    const int t = threadIdx.x;
    if (t == 0) carry_s = 0;
    __syncthreads();
    for (int base = 0; base < n; base += 1024) {
        int i = base + t;
        int v = (i < n) ? cnt[i] : 0;
        buf[t] = v;
        __syncthreads();
#pragma unroll
        for (int off = 1; off < 1024; off <<= 1) {
            int x = (t >= off) ? buf[t - off] : 0;
            __syncthreads();
            buf[t] += x;
            __syncthreads();
        }
        int carry = carry_s;
        if (i < n) row_ptr[i] = carry + buf[t] - v;  // exclusive
        __syncthreads();
        if (t == 0) carry_s = carry + buf[1023];
        __syncthreads();
    }
    if (t == 0) row_ptr[n] = carry_s;
}

__global__ void fill_kernel(const int* __restrict__ src, const int* __restrict__ dst,
                            const int* __restrict__ row_ptr, int* __restrict__ fill,
                            int* __restrict__ csr_src, int e) {
    int i = blockIdx.x * blockDim.x + threadIdx.x;
    if (i < e) {
        int d = dst[i];
        int pos = row_ptr[d] + atomicAdd(&fill[d], 1);
        csr_src[pos] = src[i];
    }
}

__global__ void dinv_kernel(const int* __restrict__ row_ptr, float* __restrict__ dinv, int n) {
    int i = blockIdx.x * blockDim.x + threadIdx.x;
    if (i < n) dinv[i] = rsqrtf((float)(row_ptr[i + 1] - row_ptr[i]) + 1.0f);
}

// ---------------- weight transpose-cast: W[K][F] fp32 -> Wt[F][K] bf16 ----------------
__global__ void wcast_kernel(const float* __restrict__ W, u16* __restrict__ Wt,
                             int lgK, int F, int total) {
    int gid = blockIdx.x * blockDim.x + threadIdx.x;
    if (gid >= total) return;
    int K = 1 << lgK;
    int k = gid & (K - 1);
    int n = gid >> lgK;
    Wt[gid] = f2bf(W[(size_t)k * F + n]);
}

// ---------------- Y = bf16(dinv[i] * x[i,:]), 128 cols ----------------
__global__ void scale_cast_kernel(const float* __restrict__ x, const float* __restrict__ dinv,
                                  u16* __restrict__ Y, int N) {
    int gid = blockIdx.x * blockDim.x + threadIdx.x;
    int node = gid >> 5;
    int c4 = (gid & 31) * 4;
    if (node >= N) return;
    float dv = dinv[node];
    float4 v = *reinterpret_cast<const float4*>(x + (size_t)node * 128 + c4);
    ushort4 r;
    r.x = f2bf(dv * v.x); r.y = f2bf(dv * v.y);
    r.z = f2bf(dv * v.z); r.w = f2bf(dv * v.w);
    *reinterpret_cast<ushort4*>(Y + (size_t)node * 128 + c4) = r;
}

// ---------------- helpers: bf16x8 accumulate / store ----------------
__device__ __forceinline__ void add8(float* acc, const u16* p) {
    short8 v = *reinterpret_cast<const short8*>(p);
#pragma unroll
    for (int w = 0; w < 8; ++w) acc[w] += bf2f((u16)v[w]);
}

// ---------------- layer-1 pre-aggregation: Z[d] = bf16(dinv[d]*(Y[d]+sum Y[src])) ----------------
__global__ void agg_pre_kernel(const int* __restrict__ row_ptr, const int* __restrict__ csr_src,
                               const u16* __restrict__ Y, const float* __restrict__ dinv,
                               u16* __restrict__ Z, int N) {
    int gid = blockIdx.x * blockDim.x + threadIdx.x;
    int node = gid >> 4;          // 16 threads/node
    int ch = (gid & 15) * 8;      // 8 cols each
    if (node >= N) return;
    float acc[8] = {};
    add8(acc, Y + (size_t)node * 128 + ch);  // self-loop
    int beg = row_ptr[node], end = row_ptr[node + 1];
    for (int e = beg; e < end; ++e) {
        int s = csr_src[e];
        add8(acc, Y + (size_t)s * 128 + ch);
    }
    float dv = dinv[node];
    short8 r;
#pragma unroll
    for (int w = 0; w < 8; ++w) r[w] = (short)f2bf(dv * acc[w]);
    *reinterpret_cast<short8*>(Z + (size_t)node * 128 + ch) = r;
}

// ---------------- MFMA bf16 GEMM ----------------
// Out[N,F] from X[N,K] bf16 and Wt[F,K] bf16.
// EPI=0: Out = bf16(dinv[row] * acc)          (pre-aggregation form)
// EPI=1: Out = bf16(relu(acc + bias[col]))    (layer-1, post-aggregated input)
// BM=128, BK=32, 256 threads = 4 waves (2x2), wave tile 64 x (BN/2).
template <int BN, int EPI>
__global__ __launch_bounds__(256) void gemm_mfma_kernel(
    const u16* __restrict__ X, const u16* __restrict__ Wt,
    const float* __restrict__ dinv, const float* __restrict__ bias,
    u16* __restrict__ Out, int N, int K, int F) {
    constexpr int BM = 128, BK = 32;
    constexpr int LDK = BK + 8;  // 40 bf16 = 80 B rows: kills LDS bank conflicts
    __shared__ u16 As[BM * LDK];
    __shared__ u16 Bs[BN * LDK];

    const int t = threadIdx.x;
    const int wave = t >> 6;
    const int lane = t & 63;
    const int m16 = lane & 15;
    const int quad = lane >> 4;

    const int row0 = blockIdx.y * BM;
    const int col0 = blockIdx.x * BN;

    constexpr int WN = BN / 2;     // wave tile cols (2x2 wave grid)
    constexpr int NI = 4;          // 4 m-subtiles of 16
    constexpr int NJ = WN / 16;    // 4 (BN=128) or 2 (BN=64)
    const int wm = (wave >> 1) * 64;
    const int wn = (wave & 1) * WN;

    f32x4 acc[NI][NJ] = {};

    for (int k0 = 0; k0 < K; k0 += BK) {
        // stage A: 128x32 bf16, 512 16B-chunks, 2 per thread
#pragma unroll
        for (int cc = 0; cc < 2; ++cc) {
            int c = t + cc * 256;
            int r = c >> 2, q = c & 3;
            int grow = row0 + r;
            short8 v = {0, 0, 0, 0, 0, 0, 0, 0};
            if (grow < N)
                v = *reinterpret_cast<const short8*>(X + (size_t)grow * K + k0 + q * 8);
            *reinterpret_cast<short8*>(&As[r * LDK + q * 8]) = v;
        }
        // stage B: BNx32 bf16
#pragma unroll
        for (int cc = 0; cc < (BN * 4) / 256; ++cc) {
            int c = t + cc * 256;
            int r = c >> 2, q = c & 3;
            short8 v = *reinterpret_cast<const short8*>(Wt + (size_t)(col0 + r) * K + k0 + q * 8);
            *reinterpret_cast<short8*>(&Bs[r * LDK + q * 8]) = v;
        }
        __syncthreads();

        short8 af[NI], bf[NJ];
#pragma unroll
        for (int i = 0; i < NI; ++i)
            af[i] = *reinterpret_cast<const short8*>(&As[(wm + i * 16 + m16) * LDK + quad * 8]);
#pragma unroll
        for (int j = 0; j < NJ; ++j)
            bf[j] = *reinterpret_cast<const short8*>(&Bs[(wn + j * 16 + m16) * LDK + quad * 8]);
#pragma unroll
        for (int i = 0; i < NI; ++i)
#pragma unroll
            for (int j = 0; j < NJ; ++j)
                acc[i][j] = __builtin_amdgcn_mfma_f32_16x16x32_bf16(af[i], bf[j], acc[i][j], 0, 0, 0);
        __syncthreads();
    }

    // epilogue: C/D layout col=lane&15, row=quad*4+reg  [measured m89/m91]
#pragma unroll
    for (int i = 0; i < NI; ++i) {
#pragma unroll
        for (int r = 0; r < 4; ++r) {
            int grow = row0 + wm + i * 16 + quad * 4 + r;
            if (grow >= N) continue;
            float dv = (EPI == 0) ? dinv[grow] : 0.f;
#pragma unroll
            for (int j = 0; j < NJ; ++j) {
                int gcol = col0 + wn + j * 16 + m16;
                float v = acc[i][j][r];
                if (EPI == 0) v = dv * v;
                else          v = fmaxf(v + bias[gcol], 0.f);
                Out[(size_t)grow * F + gcol] = f2bf(v);
            }
        }
    }
}

// ---------------- post-aggregation: X_next = bf16(relu(dinv*(G[d]+sum G[src]) + b)) ----------------
__global__ void agg_post_kernel(const int* __restrict__ row_ptr, const int* __restrict__ csr_src,
                                const u16* __restrict__ Gc, const float* __restrict__ dinv,
                                const float* __restrict__ bias, u16* __restrict__ XO,
                                int N, int F, int lgG) {
    int gid = blockIdx.x * blockDim.x + threadIdx.x;
    int node = gid >> lgG;
    int ch = (gid & ((1 << lgG) - 1)) * 8;
    if (node >= N) return;
    float acc[8] = {};
    add8(acc, Gc + (size_t)node * F + ch);  // self-loop
    int beg = row_ptr[node], end = row_ptr[node + 1];
    for (int e = beg; e < end; ++e) {
        int s = csr_src[e];
        add8(acc, Gc + (size_t)s * F + ch);
    }
    float dv = dinv[node];
    short8 r;
#pragma unroll
    for (int w = 0; w < 8; ++w)
        r[w] = (short)f2bf(fmaxf(fmaf(dv, acc[w], bias[ch + w]), 0.f));
    *reinterpret_cast<short8*>(XO + (size_t)node * F + ch) = r;
}

// ---------------- layer 5 (F_out = 1), bf16 input ----------------
__global__ void layer5_dot_kernel(const u16* __restrict__ X, const float* __restrict__ W5,
                                  const float* __restrict__ dinv, float* __restrict__ g5, int N) {
    int gtid = blockIdx.x * blockDim.x + threadIdx.x;
    int node = gtid >> 6;
    int lane = threadIdx.x & 63;
    if (node >= N) return;
    float v = bf2f(X[(size_t)node * 64 + lane]) * W5[lane];
#pragma unroll
    for (int off = 32; off > 0; off >>= 1) v += __shfl_down(v, off, 64);
    if (lane == 0) g5[node] = dinv[node] * v;
}

__global__ void agg5_kernel(const int* __restrict__ row_ptr, const int* __restrict__ csr_src,
                            const float* __restrict__ g5, const float* __restrict__ dinv,
                            const float* __restrict__ b5, float* __restrict__ out, int N) {
    int i = blockIdx.x * blockDim.x + threadIdx.x;
    if (i >= N) return;
    float acc = g5[i];
    for (int e = row_ptr[i]; e < row_ptr[i + 1]; ++e) acc += g5[csr_src[e]];
    out[i] = fmaxf(fmaf(dinv[i], acc, b5[0]), 0.f);
}

// ---------------- launch ----------------

static inline size_t align_up(size_t x) { return (x + 255) & ~(size_t)255; }

extern "C" void kernel_launch(void* const* d_in, const int* in_sizes, int n_in,
                              void* d_out, int out_size, void* d_ws, size_t ws_size,
                              hipStream_t stream) {
    const float* x  = (const float*)d_in[0];
    const int*   ei = (const int*)d_in[1];
    const int E = in_sizes[1] / 2;
    const int N = in_sizes[0] / N_NODES_DIM0;
    const int* src = ei;
    const int* dst = ei + E;

    const float* W[5] = {(const float*)d_in[2], (const float*)d_in[4], (const float*)d_in[6],
                         (const float*)d_in[8], (const float*)d_in[10]};
    const float* B[5] = {(const float*)d_in[3], (const float*)d_in[5], (const float*)d_in[7],
                         (const float*)d_in[9], (const float*)d_in[11]};

    const int Ks[4] = {128, 1024, 512, 256};
    const int Fs[4] = {1024, 512, 256, 64};
    const int lgKs[4] = {7, 10, 9, 8};

    // workspace carve — peak ~209 MB
    char* w = (char*)d_ws;
    size_t off = 0;
    float* dinv    = (float*)(w + off); off += align_up((size_t)N * 4);
    float* g5      = (float*)(w + off); off += align_up((size_t)N * 4);
    int*   cnt     = (int*)(w + off);   off += align_up((size_t)N * 4);         // reused as fill[]
    int*   row_ptr = (int*)(w + off);   off += align_up((size_t)(N + 1) * 4);
    int*   csr_src = (int*)(w + off);   off += align_up((size_t)E * 4);         // 1.6 MB
    u16*   Wt[4];
    for (int l = 0; l < 4; ++l) {
        Wt[l] = (u16*)(w + off);
        off += align_up((size_t)Ks[l] * Fs[l] * 2);
    }
    // Gc region (51.2 MB) also hosts Y+Z (12.8+12.8 MB), used only before layer-2 GEMM
    char* REG = w + off;               off += align_up((size_t)N * 512 * 2);    // 51.2 MB
    u16* Y  = (u16*)REG;
    u16* Z  = (u16*)(REG + align_up((size_t)N * 128 * 2));
    u16* Gc = (u16*)REG;
    u16* XA = (u16*)(w + off);         off += align_up((size_t)N * 1024 * 2);   // 102.4 MB
    u16* XB = (u16*)(w + off);         off += align_up((size_t)N * 512 * 2);    // 51.2 MB
    (void)ws_size;

    // ---- CSR build (dst-sorted) ----
    zero_int_kernel<<<(N + 255) / 256, 256, 0, stream>>>(cnt, N);
    hist_kernel<<<(E + 255) / 256, 256, 0, stream>>>(dst, cnt, E);
    scan_kernel<<<1, 1024, 0, stream>>>(cnt, row_ptr, N);
    zero_int_kernel<<<(N + 255) / 256, 256, 0, stream>>>(cnt, N);  // reuse as fill
    fill_kernel<<<(E + 255) / 256, 256, 0, stream>>>(src, dst, row_ptr, cnt, csr_src, E);
    dinv_kernel<<<(N + 255) / 256, 256, 0, stream>>>(row_ptr, dinv, N);

    // ---- weights -> Wt bf16 [F][K] ----
    for (int l = 0; l < 4; ++l) {
        int total = Ks[l] * Fs[l];
        wcast_kernel<<<(total + 255) / 256, 256, 0, stream>>>(W[l], Wt[l], lgKs[l], Fs[l], total);
    }

    // ---- layer 1: aggregate-first (K=128 < F=1024) ----
    scale_cast_kernel<<<(N * 32 + 255) / 256, 256, 0, stream>>>(x, dinv, Y, N);
    agg_pre_kernel<<<(N * 16 + 255) / 256, 256, 0, stream>>>(row_ptr, csr_src, Y, dinv, Z, N);
    {
        dim3 g(1024 / 128, (N + 127) / 128);
        gemm_mfma_kernel<128, 1><<<g, 256, 0, stream>>>(Z, Wt[0], dinv, B[0], XA, N, 128, 1024);
    }

    // ---- layers 2..4: GEMM (dinv epilogue) -> aggregate (bias+relu) ----
    u16* Xin[3]  = {XA, XB, XA};
    u16* Xout[3] = {XB, XA, XB};
    for (int l = 1; l < 4; ++l) {
        const int K = Ks[l], F = Fs[l];
        if (F >= 128) {
            dim3 g(F / 128, (N + 127) / 128);
            gemm_mfma_kernel<128, 0><<<g, 256, 0, stream>>>(Xin[l - 1], Wt[l], dinv, B[l], Gc, N, K, F);
        } else {
            dim3 g(F / 64, (N + 127) / 128);
            gemm_mfma_kernel<64, 0><<<g, 256, 0, stream>>>(Xin[l - 1], Wt[l], dinv, B[l], Gc, N, K, F);
        }
        int lgG = (F == 512) ? 6 : (F == 256) ? 5 : 3;  // F/8 threads per node
        long long tot = (long long)N << lgG;
        agg_post_kernel<<<(unsigned)((tot + 255) / 256), 256, 0, stream>>>(
            row_ptr, csr_src, Gc, dinv, B[l], Xout[l - 1], N, F, lgG);
    }

    // ---- layer 5: [N,64](bf16) @ [64,1] ----
    layer5_dot_kernel<<<(N * 64 + 255) / 256, 256, 0, stream>>>(XB, W[4], dinv, g5, N);
    agg5_kernel<<<(N + 255) / 256, 256, 0, stream>>>(row_ptr, csr_src, g5, dinv, B[4],
                                                     (float*)d_out, N);
}

// Round 5
// 580.489 us; speedup vs baseline: 20.8172x; 1.0730x over previous
//
#include <hip/hip_runtime.h>
#include <hip/hip_bf16.h>

#define N_NODES_DIM0 128

typedef unsigned short u16;
typedef unsigned int u32;
typedef __attribute__((ext_vector_type(8))) short short8;
typedef __attribute__((ext_vector_type(4))) float f32x4;

__device__ __forceinline__ float bf2f(u16 h) { return __uint_as_float((u32)h << 16); }
__device__ __forceinline__ u16 f2bf(float f) {
    u32 u = __float_as_uint(f);
    u32 r = (u + 0x7FFFu + ((u >> 16) & 1u)) >> 16;  // round-to-nearest-even
    return (u16)r;
}

// async global->LDS, 16 B per lane; lds dest = wave-uniform base + lane*16
__device__ __forceinline__ void gl2lds16(const u16* g, u16* lds_base) {
    __builtin_amdgcn_global_load_lds(
        (const __attribute__((address_space(1))) u32*)g,
        (__attribute__((address_space(3))) u32*)lds_base, 16, 0, 0);
}

// ---------------- CSR build ----------------

__global__ void zero_int_kernel(int* p, int n) {
    int i = blockIdx.x * blockDim.x + threadIdx.x;
    if (i < n) p[i] = 0;
}

__global__ void hist_kernel(const int* __restrict__ dst, int* __restrict__ cnt, int e) {
    int i = blockIdx.x * blockDim.x + threadIdx.x;
    if (i < e) atomicAdd(&cnt[dst[i]], 1);
}

// single-workgroup chunked exclusive scan: row_ptr[0..n], row_ptr[n] = total
__global__ __launch_bounds__(1024) void scan_kernel(const int* __restrict__ cnt,
                                                    int* __restrict__ row_ptr, int n) {
    __shared__ int buf[1024];
    __shared__ int carry_s;
    const int t = threadIdx.x;
    if (t == 0) carry_s = 0;
    __syncthreads();
    for (int base = 0; base < n; base += 1024) {
        int i = base + t;
        int v = (i < n) ? cnt[i] : 0;
        buf[t] = v;
        __syncthreads();
#pragma unroll
        for (int off = 1; off < 1024; off <<= 1) {
            int x = (t >= off) ? buf[t - off] : 0;
            __syncthreads();
            buf[t] += x;
            __syncthreads();
        }
        int carry = carry_s;
        if (i < n) row_ptr[i] = carry + buf[t] - v;  // exclusive
        __syncthreads();
        if (t == 0) carry_s = carry + buf[1023];
        __syncthreads();
    }
    if (t == 0) row_ptr[n] = carry_s;
}

__global__ void fill_kernel(const int* __restrict__ src, const int* __restrict__ dst,
                            const int* __restrict__ row_ptr, int* __restrict__ fill,
                            int* __restrict__ csr_src, int e) {
    int i = blockIdx.x * blockDim.x + threadIdx.x;
    if (i < e) {
        int d = dst[i];
        int pos = row_ptr[d] + atomicAdd(&fill[d], 1);
        csr_src[pos] = src[i];
    }
}

__global__ void dinv_kernel(const int* __restrict__ row_ptr, float* __restrict__ dinv, int n) {
    int i = blockIdx.x * blockDim.x + threadIdx.x;
    if (i < n) dinv[i] = rsqrtf((float)(row_ptr[i + 1] - row_ptr[i]) + 1.0f);
}

// ---------------- weight transpose-cast: W[K][F] fp32 -> Wt[F][K] bf16 ----------------
__global__ void wcast_kernel(const float* __restrict__ W, u16* __restrict__ Wt,
                             int lgK, int F, int total) {
    int gid = blockIdx.x * blockDim.x + threadIdx.x;
    if (gid >= total) return;
    int K = 1 << lgK;
    int k = gid & (K - 1);
    int n = gid >> lgK;
    Wt[gid] = f2bf(W[(size_t)k * F + n]);
}

// ---------------- Y = bf16(dinv[i] * x[i,:]), 128 cols ----------------
__global__ void scale_cast_kernel(const float* __restrict__ x, const float* __restrict__ dinv,
                                  u16* __restrict__ Y, int N) {
    int gid = blockIdx.x * blockDim.x + threadIdx.x;
    int node = gid >> 5;
    int c4 = (gid & 31) * 4;
    if (node >= N) return;
    float dv = dinv[node];
    float4 v = *reinterpret_cast<const float4*>(x + (size_t)node * 128 + c4);
    ushort4 r;
    r.x = f2bf(dv * v.x); r.y = f2bf(dv * v.y);
    r.z = f2bf(dv * v.z); r.w = f2bf(dv * v.w);
    *reinterpret_cast<ushort4*>(Y + (size_t)node * 128 + c4) = r;
}

// ---------------- helpers: bf16x8 accumulate ----------------
__device__ __forceinline__ void add8(float* acc, const u16* p) {
    short8 v = *reinterpret_cast<const short8*>(p);
#pragma unroll
    for (int w = 0; w < 8; ++w) acc[w] += bf2f((u16)v[w]);
}

// ---------------- layer-1 pre-aggregation: Z[d] = bf16(dinv[d]*(Y[d]+sum Y[src])) ----------------
__global__ void agg_pre_kernel(const int* __restrict__ row_ptr, const int* __restrict__ csr_src,
                               const u16* __restrict__ Y, const float* __restrict__ dinv,
                               u16* __restrict__ Z, int N) {
    int gid = blockIdx.x * blockDim.x + threadIdx.x;
    int node = gid >> 4;          // 16 threads/node
    int ch = (gid & 15) * 8;      // 8 cols each
    if (node >= N) return;
    float acc[8] = {};
    add8(acc, Y + (size_t)node * 128 + ch);  // self-loop
    int beg = row_ptr[node], end = row_ptr[node + 1];
    for (int e = beg; e < end; ++e) {
        int s = csr_src[e];
        add8(acc, Y + (size_t)s * 128 + ch);
    }
    float dv = dinv[node];
    short8 r;
#pragma unroll
    for (int w = 0; w < 8; ++w) r[w] = (short)f2bf(dv * acc[w]);
    *reinterpret_cast<short8*>(Z + (size_t)node * 128 + ch) = r;
}

// ---------------- MFMA bf16 GEMM (global_load_lds staging + XCD swizzle) ----------------
// Out[N,F] from X[N,K] bf16 and Wt[F,K] bf16.
// EPI=0: Out = bf16(dinv[row] * acc)       EPI=1: Out = bf16(relu(acc + bias[col]))
// BM=128, BK=32, 256 threads = 4 waves (2x2), wave tile 64 x (BN/2).
// LDS rows are 5 chunks of 16B (4 data + 1 pad) -> 80 B stride, conflict-minimal.
// Grid: 1-D, groups of 8 row-blocks x nx col-blocks so same-row col-blocks
// share an XCD (id%8 = row-in-group under round-robin block->XCD dispatch).
template <int BN, int EPI>
__global__ __launch_bounds__(256) void gemm_mfma_kernel(
    const u16* __restrict__ X, const u16* __restrict__ Wt,
    const float* __restrict__ dinv, const float* __restrict__ bias,
    u16* __restrict__ Out, int N, int K, int F, int lgnx) {
    constexpr int BM = 128, BK = 32;
    constexpr int LDK = BK + 8;          // 40 u16 = 80 B per row
    constexpr int CHA = BM * 5;          // 640 16B-chunks for A
    constexpr int CHB = BN * 5;          // 640 / 320 for B
    __shared__ u16 As[BM * LDK];
    __shared__ u16 Bs[BN * LDK];

    const int t = threadIdx.x;
    const int wave = t >> 6;
    const int lane = t & 63;
    const int m16 = lane & 15;
    const int quad = lane >> 4;

    // XCD-aware decode
    const int id = blockIdx.x;
    const int wi = id & ((8 << lgnx) - 1);
    const int g  = id >> (3 + lgnx);
    const int rb = g * 8 + (wi & 7);
    const int cb = wi >> 3;
    const int row0 = rb * BM;
    const int col0 = cb * BN;
    if (row0 >= N) return;

    constexpr int WN = BN / 2;
    constexpr int NI = 4;
    constexpr int NJ = WN / 16;
    const int wm = (wave >> 1) * 64;
    const int wn = (wave & 1) * WN;

    f32x4 acc[NI][NJ] = {};

    for (int k0 = 0; k0 < K; k0 += BK) {
        // stage A: chunks c -> row c/5, sub c%5 (sub 4 = pad, harmless dup load)
        for (int cbase = 0; cbase < CHA; cbase += 256) {
            int rem = CHA - cbase;
            if (wave * 64 < rem) {  // wave-uniform
                int c = cbase + wave * 64 + lane;
                int r = c / 5;
                int q = (c - r * 5) & 3;
                int grow = row0 + r;
                if (grow >= N) grow = 0;  // clamp; epilogue guards rows >= N
                const u16* gp = X + (size_t)grow * K + k0 + q * 8;
                gl2lds16(gp, &As[(size_t)(cbase + wave * 64) * 8]);
            }
        }
        // stage B
        for (int cbase = 0; cbase < CHB; cbase += 256) {
            int rem = CHB - cbase;
            if (wave * 64 < rem) {
                int c = cbase + wave * 64 + lane;
                int r = c / 5;
                int q = (c - r * 5) & 3;
                const u16* gp = Wt + (size_t)(col0 + r) * K + k0 + q * 8;
                gl2lds16(gp, &Bs[(size_t)(cbase + wave * 64) * 8]);
            }
        }
        __syncthreads();  // drains vmcnt (compiler-inserted) -> LDS valid

        short8 af[NI], bf[NJ];
#pragma unroll
        for (int i = 0; i < NI; ++i)
            af[i] = *reinterpret_cast<const short8*>(&As[(wm + i * 16 + m16) * LDK + quad * 8]);
#pragma unroll
        for (int j = 0; j < NJ; ++j)
            bf[j] = *reinterpret_cast<const short8*>(&Bs[(wn + j * 16 + m16) * LDK + quad * 8]);
#pragma unroll
        for (int i = 0; i < NI; ++i)
#pragma unroll
            for (int j = 0; j < NJ; ++j)
                acc[i][j] = __builtin_amdgcn_mfma_f32_16x16x32_bf16(af[i], bf[j], acc[i][j], 0, 0, 0);
        __syncthreads();
    }

    // epilogue: C/D layout col=lane&15, row=quad*4+reg  [measured m89/m91]
#pragma unroll
    for (int i = 0; i < NI; ++i) {
#pragma unroll
        for (int r = 0; r < 4; ++r) {
            int grow = row0 + wm + i * 16 + quad * 4 + r;
            if (grow >= N) continue;
            float dv = (EPI == 0) ? dinv[grow] : 0.f;
#pragma unroll
            for (int j = 0; j < NJ; ++j) {
                int gcol = col0 + wn + j * 16 + m16;
                float v = acc[i][j][r];
                if (EPI == 0) v = dv * v;
                else          v = fmaxf(v + bias[gcol], 0.f);
                Out[(size_t)grow * F + gcol] = f2bf(v);
            }
        }
    }
}

// ---------------- post-aggregation: X_next = bf16(relu(dinv*(G[d]+sum G[src]) + b)) ----------------
__global__ void agg_post_kernel(const int* __restrict__ row_ptr, const int* __restrict__ csr_src,
                                const u16* __restrict__ Gc, const float* __restrict__ dinv,
                                const float* __restrict__ bias, u16* __restrict__ XO,
                                int N, int F, int lgG) {
    int gid = blockIdx.x * blockDim.x + threadIdx.x;
    int node = gid >> lgG;
    int ch = (gid & ((1 << lgG) - 1)) * 8;
    if (node >= N) return;
    float acc[8] = {};
    add8(acc, Gc + (size_t)node * F + ch);  // self-loop
    int beg = row_ptr[node], end = row_ptr[node + 1];
    for (int e = beg; e < end; ++e) {
        int s = csr_src[e];
        add8(acc, Gc + (size_t)s * F + ch);
    }
    float dv = dinv[node];
    short8 r;
#pragma unroll
    for (int w = 0; w < 8; ++w)
        r[w] = (short)f2bf(fmaxf(fmaf(dv, acc[w], bias[ch + w]), 0.f));
    *reinterpret_cast<short8*>(XO + (size_t)node * F + ch) = r;
}

// ---------------- layer 5 (F_out = 1), bf16 input ----------------
__global__ void layer5_dot_kernel(const u16* __restrict__ X, const float* __restrict__ W5,
                                  const float* __restrict__ dinv, float* __restrict__ g5, int N) {
    int gtid = blockIdx.x * blockDim.x + threadIdx.x;
    int node = gtid >> 6;
    int lane = threadIdx.x & 63;
    if (node >= N) return;
    float v = bf2f(X[(size_t)node * 64 + lane]) * W5[lane];
#pragma unroll
    for (int off = 32; off > 0; off >>= 1) v += __shfl_down(v, off, 64);
    if (lane == 0) g5[node] = dinv[node] * v;
}

__global__ void agg5_kernel(const int* __restrict__ row_ptr, const int* __restrict__ csr_src,
                            const float* __restrict__ g5, const float* __restrict__ dinv,
                            const float* __restrict__ b5, float* __restrict__ out, int N) {
    int i = blockIdx.x * blockDim.x + threadIdx.x;
    if (i >= N) return;
    float acc = g5[i];
    for (int e = row_ptr[i]; e < row_ptr[i + 1]; ++e) acc += g5[csr_src[e]];
    out[i] = fmaxf(fmaf(dinv[i], acc, b5[0]), 0.f);
}

// ---------------- launch ----------------

static inline size_t align_up(size_t x) { return (x + 255) & ~(size_t)255; }
static inline int round_up8(int x) { return (x + 7) & ~7; }

extern "C" void kernel_launch(void* const* d_in, const int* in_sizes, int n_in,
                              void* d_out, int out_size, void* d_ws, size_t ws_size,
                              hipStream_t stream) {
    const float* x  = (const float*)d_in[0];
    const int*   ei = (const int*)d_in[1];
    const int E = in_sizes[1] / 2;
    const int N = in_sizes[0] / N_NODES_DIM0;
    const int* src = ei;
    const int* dst = ei + E;

    const float* W[5] = {(const float*)d_in[2], (const float*)d_in[4], (const float*)d_in[6],
                         (const float*)d_in[8], (const float*)d_in[10]};
    const float* B[5] = {(const float*)d_in[3], (const float*)d_in[5], (const float*)d_in[7],
                         (const float*)d_in[9], (const float*)d_in[11]};

    const int Ks[4] = {128, 1024, 512, 256};
    const int Fs[4] = {1024, 512, 256, 64};
    const int lgKs[4] = {7, 10, 9, 8};

    // workspace carve — peak ~209 MB
    char* w = (char*)d_ws;
    size_t off = 0;
    float* dinv    = (float*)(w + off); off += align_up((size_t)N * 4);
    float* g5      = (float*)(w + off); off += align_up((size_t)N * 4);
    int*   cnt     = (int*)(w + off);   off += align_up((size_t)N * 4);         // reused as fill[]
    int*   row_ptr = (int*)(w + off);   off += align_up((size_t)(N + 1) * 4);
    int*   csr_src = (int*)(w + off);   off += align_up((size_t)E * 4);         // 1.6 MB
    u16*   Wt[4];
    for (int l = 0; l < 4; ++l) {
        Wt[l] = (u16*)(w + off);
        off += align_up((size_t)Ks[l] * Fs[l] * 2);
    }
    // Gc region (51.2 MB) also hosts Y+Z (12.8+12.8 MB), used only before layer-2 GEMM
    char* REG = w + off;               off += align_up((size_t)N * 512 * 2);    // 51.2 MB
    u16* Y  = (u16*)REG;
    u16* Z  = (u16*)(REG + align_up((size_t)N * 128 * 2));
    u16* Gc = (u16*)REG;
    u16* XA = (u16*)(w + off);         off += align_up((size_t)N * 1024 * 2);   // 102.4 MB
    u16* XB = (u16*)(w + off);         off += align_up((size_t)N * 512 * 2);    // 51.2 MB
    (void)ws_size;

    // ---- CSR build (dst-sorted) ----
    zero_int_kernel<<<(N + 255) / 256, 256, 0, stream>>>(cnt, N);
    hist_kernel<<<(E + 255) / 256, 256, 0, stream>>>(dst, cnt, E);
    scan_kernel<<<1, 1024, 0, stream>>>(cnt, row_ptr, N);
    zero_int_kernel<<<(N + 255) / 256, 256, 0, stream>>>(cnt, N);  // reuse as fill
    fill_kernel<<<(E + 255) / 256, 256, 0, stream>>>(src, dst, row_ptr, cnt, csr_src, E);
    dinv_kernel<<<(N + 255) / 256, 256, 0, stream>>>(row_ptr, dinv, N);

    // ---- weights -> Wt bf16 [F][K] ----
    for (int l = 0; l < 4; ++l) {
        int total = Ks[l] * Fs[l];
        wcast_kernel<<<(total + 255) / 256, 256, 0, stream>>>(W[l], Wt[l], lgKs[l], Fs[l], total);
    }

    const int ny = (N + 127) / 128;
    const int ny8 = round_up8(ny);

    // ---- layer 1: aggregate-first (K=128 < F=1024) ----
    scale_cast_kernel<<<(N * 32 + 255) / 256, 256, 0, stream>>>(x, dinv, Y, N);
    agg_pre_kernel<<<(N * 16 + 255) / 256, 256, 0, stream>>>(row_ptr, csr_src, Y, dinv, Z, N);
    {
        // F=1024, BN=128 -> nx=8, lgnx=3
        gemm_mfma_kernel<128, 1><<<ny8 * 8, 256, 0, stream>>>(Z, Wt[0], dinv, B[0], XA,
                                                              N, 128, 1024, 3);
    }

    // ---- layers 2..4: GEMM (dinv epilogue) -> aggregate (bias+relu) ----
    u16* Xin[3]  = {XA, XB, XA};
    u16* Xout[3] = {XB, XA, XB};
    for (int l = 1; l < 4; ++l) {
        const int K = Ks[l], F = Fs[l];
        if (F >= 128) {
            int nx = F / 128;
            int lgnx = (nx == 4) ? 2 : (nx == 2) ? 1 : 0;
            gemm_mfma_kernel<128, 0><<<ny8 * nx, 256, 0, stream>>>(
                Xin[l - 1], Wt[l], dinv, B[l], Gc, N, K, F, lgnx);
        } else {
            // F=64, BN=64 -> nx=1, lgnx=0
            gemm_mfma_kernel<64, 0><<<ny8, 256, 0, stream>>>(
                Xin[l - 1], Wt[l], dinv, B[l], Gc, N, K, F, 0);
        }
        int lgG = (F == 512) ? 6 : (F == 256) ? 5 : 3;  // F/8 threads per node
        long long tot = (long long)N << lgG;
        agg_post_kernel<<<(unsigned)((tot + 255) / 256), 256, 0, stream>>>(
            row_ptr, csr_src, Gc, dinv, B[l], Xout[l - 1], N, F, lgG);
    }

    // ---- layer 5: [N,64](bf16) @ [64,1] ----
    layer5_dot_kernel<<<(N * 64 + 255) / 256, 256, 0, stream>>>(XB, W[4], dinv, g5, N);
    agg5_kernel<<<(N + 255) / 256, 256, 0, stream>>>(row_ptr, csr_src, g5, dinv, B[4],
                                                     (float*)d_out, N);
}